// Round 6
// baseline (303.337 us; speedup 1.0000x reference)
//
#include <hip/hip_runtime.h>

typedef __attribute__((ext_vector_type(8))) short short8;
typedef __attribute__((ext_vector_type(4))) float f32x4;
typedef __attribute__((ext_vector_type(4))) unsigned short u16x4;
typedef __attribute__((ext_vector_type(2))) unsigned int u32x2;

#define MFMA16(a,b,c) __builtin_amdgcn_mfma_f32_16x16x32_bf16((a),(b),(c),0,0,0)

// 0.125 (attn scale) * log2(e), folded into Q at the QKV epilogue.
#define QSCALE 0.1803368801f

__device__ __forceinline__ unsigned short f2bf(float f) {
  unsigned int x = __float_as_uint(f);
  x += 0x7fffu + ((x >> 16) & 1u);
  return (unsigned short)(x >> 16);
}
__device__ __forceinline__ unsigned int pack2bf(float a, float b) {
  unsigned int ua = __float_as_uint(a) + 0x8000u;
  unsigned int ub = __float_as_uint(b) + 0x8000u;
  return __builtin_amdgcn_perm(ub, ua, 0x07060302);
}
// async 16B global -> LDS (dest must vary as wave-uniform base + lane*16)
__device__ __forceinline__ void gload16(const unsigned short* g, unsigned short* l) {
  __builtin_amdgcn_global_load_lds(
      (const __attribute__((address_space(1))) unsigned int*)g,
      (__attribute__((address_space(3))) unsigned int*)l, 16, 0, 0);
}

// ---------------------------------------------------------------------------
// Kernel 1: prep = convert_x (blocks < 6144) + build_weights (rest).
// ---------------------------------------------------------------------------
__global__ __launch_bounds__(256) void prep(
    const float* __restrict__ x,
    const float* __restrict__ w_qkv,
    const float* __restrict__ w_proj,
    const float* __restrict__ q_a, const float* __restrict__ q_b,
    const float* __restrict__ k_a, const float* __restrict__ k_b,
    const float* __restrict__ v_a, const float* __restrict__ v_b,
    const float* __restrict__ o_a, const float* __restrict__ o_b,
    unsigned short* __restrict__ xb,
    unsigned short* __restrict__ wqkv_eff,
    unsigned short* __restrict__ wproj_eff)
{
  int bid = blockIdx.x;
  if (bid < 6144) {
    int i4 = (bid * 256 + threadIdx.x) * 4;
    f32x4 v = *(const f32x4*)&x[i4];
    u16x4 o;
    o.x = f2bf(v.x); o.y = f2bf(v.y); o.z = f2bf(v.z); o.w = f2bf(v.w);
    *(u16x4*)&xb[i4] = o;
    return;
  }
  const int QKV = 2304 * 768;
  int idx = (bid - 6144) * 256 + threadIdx.x;
  if (idx < QKV) {
    int n = idx / 768, c = idx - n * 768;
    int sec = n / 768;
    int nr = n - sec * 768;
    const float* a; const float* b;
    if (sec == 0)      { a = q_a; b = q_b; }
    else if (sec == 1) { a = k_a; b = k_b; }
    else               { a = v_a; b = v_b; }
    float acc = w_qkv[idx];
    #pragma unroll
    for (int r = 0; r < 8; r++)
      acc += b[nr * 8 + r] * a[r * 768 + c];
    wqkv_eff[idx] = f2bf(acc);
  } else {
    int i2 = idx - QKV;
    int n = i2 / 768, c = i2 - n * 768;
    float acc = w_proj[i2];
    #pragma unroll
    for (int r = 0; r < 8; r++)
      acc += o_b[n * 8 + r] * o_a[r * 768 + c];
    wproj_eff[i2] = f2bf(acc);
  }
}

// ---------------------------------------------------------------------------
// Kernel 2/4: C[M,N'] = A[M,K] @ W[N',K]^T + bias. Pipelined 1-barrier K-loop:
//  - A fragments load global->register directly (rows disjoint per wave),
//    prefetched one iteration ahead (dual register set, unroll-by-2).
//  - W staged via async global_load_lds into a DOUBLE-buffered unpadded
//    XOR-swizzled LDS tile; stage (k+1) issued after the barrier, compute
//    reads buf k -> the pre-barrier vmcnt(0) drain covers loads that had a
//    full compute phase in flight (no exposed latency).
// 128x128 tile, BK=64, 2x2 wave grid, 64x64 out/wave (4x4 16x16x32 MFMA).
// mode 0 (QKV): Q*QSCALE -> q[BH][N][64]; K -> k[BH][N][64];
//               V -> vt[BH][64][1024], key-permuted cols (4*(np&15)+((np>>4)&3)).
// mode 1: fp32 row-major store (final output). Requires (K/64) even.
// ---------------------------------------------------------------------------
#define GEMM_STEP(kk, p, CUR, NXT)                                            \
  {                                                                           \
    __syncthreads();                                                          \
    const int kn_ = ((kk) + 1) << 6;                                          \
    if (kn_ < K) {                                                            \
      _Pragma("unroll")                                                       \
      for (int t = 0; t < 4; t++)                                             \
        gload16(gW[t] + kn_, ws_ + (1 - (p)) * (128 * 64) + lw_off[t]);       \
      _Pragma("unroll")                                                       \
      for (int t = 0; t < 4; t++) {                                           \
        NXT[2 * t]     = *(const short8*)&gA[(size_t)t * 16 * K + kn_];       \
        NXT[2 * t + 1] = *(const short8*)&gA[(size_t)t * 16 * K + kn_ + 32];  \
      }                                                                       \
    }                                                                         \
    _Pragma("unroll")                                                         \
    for (int ks = 0; ks < 2; ks++) {                                          \
      const int cs = ks * 4 + quad;                                           \
      short8 b_[4];                                                           \
      _Pragma("unroll")                                                       \
      for (int t = 0; t < 4; t++)                                             \
        b_[t] = *(const short8*)&ws_[(p) * (128 * 64) +                       \
                 (wc * 64 + t * 16 + l16) * 64 + ((cs ^ swz) << 3)];          \
      _Pragma("unroll")                                                       \
      for (int i = 0; i < 4; i++)                                             \
        _Pragma("unroll")                                                     \
        for (int j = 0; j < 4; j++)                                           \
          acc[i][j] = MFMA16(CUR[2 * i + ks], b_[j], acc[i][j]);              \
    }                                                                         \
  }

__global__ __launch_bounds__(256, 3) void gemm_bt(
    const unsigned short* __restrict__ A,
    const unsigned short* __restrict__ W,
    const float* __restrict__ bias,
    unsigned short* __restrict__ out0,
    unsigned short* __restrict__ out1,
    unsigned short* __restrict__ out2,
    float* __restrict__ outf,
    int K, int Ncols, int mode)
{
  __shared__ alignas(16) unsigned short Ws[2 * 128 * 64];   // 32 KB double buffer
  unsigned short* ws_ = &Ws[0];
  const int tid  = threadIdx.x;
  const int wave = tid >> 6;
  const int lane = tid & 63;
  const int quad = lane >> 4;
  const int l16  = lane & 15;
  const int wr   = wave >> 1, wc = wave & 1;   // 2x2 wave grid
  const int m0 = blockIdx.x * 128;
  const int n0 = blockIdx.y * 128;
  const int swz = l16 & 7;

  // W staging: wave stages rows [wave*32, +32), 4 instrs x 8 rows;
  // lane -> row +(lane>>3), swizzled chunk (lane&7)^(row&7); LDS dest = base+lane*16.
  const int lrow   = lane >> 3;
  const int lchunk = (lane & 7) ^ lrow;
  const unsigned short* gW[4];
  int lw_off[4];
  #pragma unroll
  for (int t = 0; t < 4; t++) {
    int rr = wave * 32 + t * 8;
    gW[t]     = W + (size_t)(n0 + rr + lrow) * K + lchunk * 8;
    lw_off[t] = (rr + lrow) * 64 + (lane & 7) * 8;
  }
  // A direct-to-register: frag(i,ks) = 16B at row m0+wr*64+i*16+l16, col ks*32+quad*8.
  const unsigned short* gA = A + (size_t)(m0 + wr * 64 + l16) * K + quad * 8;

  f32x4 acc[4][4] = {};
  short8 aA[8], aB[8];

  // prologue: stage W(0) into buf 0, load A(0)
  #pragma unroll
  for (int t = 0; t < 4; t++) gload16(gW[t], ws_ + lw_off[t]);
  #pragma unroll
  for (int t = 0; t < 4; t++) {
    aA[2 * t]     = *(const short8*)&gA[(size_t)t * 16 * K];
    aA[2 * t + 1] = *(const short8*)&gA[(size_t)t * 16 * K + 32];
  }

  const int nit = K >> 6;                      // must be even (768/64 = 12)
  for (int k = 0; k < nit; k += 2) {
    GEMM_STEP(k,     0, aA, aB);
    GEMM_STEP(k + 1, 1, aB, aA);
  }

  float bv[4];
  #pragma unroll
  for (int j = 0; j < 4; j++) bv[j] = bias[n0 + wc * 64 + j * 16 + l16];

  if (mode == 0) {
    const int sec = n0 / 768;                       // uniform (768 % 128 == 0)
    const int h   = ((n0 % 768) >> 6) + wc;         // wave's head
    unsigned short* dst = (sec == 0) ? out0 : ((sec == 1) ? out1 : out2);
    const float scl = (sec == 0) ? QSCALE : 1.0f;
    #pragma unroll
    for (int i = 0; i < 4; i++) {
      #pragma unroll
      for (int r = 0; r < 4; r++) {
        int m  = m0 + wr * 64 + i * 16 + quad * 4 + r;
        int bb = m >> 10, np = m & 1023;
        int bh = bb * 12 + h;
        int npp = (np & ~63) | ((np & 15) * 4 + ((np >> 4) & 3)); // key perm
        #pragma unroll
        for (int j = 0; j < 4; j++) {
          int d = j * 16 + l16;
          float v = (acc[i][j][r] + bv[j]) * scl;
          if (sec < 2) dst[((size_t)bh << 16) + ((size_t)np << 6) + d] = f2bf(v);
          else         dst[((size_t)bh << 16) + ((size_t)d << 10) + npp] = f2bf(v);
        }
      }
    }
  } else {
    #pragma unroll
    for (int i = 0; i < 4; i++) {
      #pragma unroll
      for (int r = 0; r < 4; r++) {
        int m = m0 + wr * 64 + i * 16 + quad * 4 + r;
        #pragma unroll
        for (int j = 0; j < 4; j++)
          outf[(size_t)m * Ncols + n0 + wc * 64 + j * 16 + l16] = acc[i][j][r] + bv[j];
      }
    }
  }
}

// ---------------------------------------------------------------------------
// Kernel 3: flash attention (unchanged — attack next round with fresh counters).
// ---------------------------------------------------------------------------
__global__ __launch_bounds__(256) void attn(
    const unsigned short* __restrict__ q,
    const unsigned short* __restrict__ k,
    const unsigned short* __restrict__ vt,
    unsigned short* __restrict__ o)
{
  __shared__ alignas(16) unsigned short Qs[128][72];
  __shared__ alignas(16) unsigned short Ks[64][72];
  __shared__ alignas(16) unsigned short Vs[64][72];
  const int tid  = threadIdx.x;
  const int wave = tid >> 6;
  const int lane = tid & 63;
  const int quad = lane >> 4;
  const int l16  = lane & 15;
  const int bh = blockIdx.x;
  const int q0 = blockIdx.y * 128;
  const unsigned short* qb = q  + ((size_t)bh << 16);
  const unsigned short* kb = k  + ((size_t)bh << 16);
  const unsigned short* vb = vt + ((size_t)bh << 16);

  #pragma unroll
  for (int i = 0; i < 4; i++) {
    int flat = tid + i * 256;
    int r = flat >> 3, ck = (flat & 7) << 3;
    *(f32x4*)&Qs[r][ck] = *(const f32x4*)&qb[((size_t)(q0 + r) << 6) + ck];
  }
  __syncthreads();
  short8 aq[2][2];
  #pragma unroll
  for (int rg = 0; rg < 2; rg++)
    #pragma unroll
    for (int ks = 0; ks < 2; ks++)
      aq[rg][ks] = *(const short8*)&Qs[wave * 32 + rg * 16 + l16][ks * 32 + quad * 8];
  __syncthreads();  // Q consumed; Qs becomes wave-private P scratch
  unsigned short (*Ps)[72] = (unsigned short (*)[72])(&Qs[wave * 32][0]);

  f32x4 Oacc[2][4] = {};
  float lsum[2][4] = {};

  int sr[2], sc[2];
  #pragma unroll
  for (int i = 0; i < 2; i++) { int f = tid + i * 256; sr[i] = f >> 3; sc[i] = (f & 7) << 3; }

  f32x4 kreg[2], vreg[2];
  #pragma unroll
  for (int i = 0; i < 2; i++) {
    kreg[i] = *(const f32x4*)&kb[((size_t)sr[i] << 6) + sc[i]];
    vreg[i] = *(const f32x4*)&vb[((size_t)sr[i] << 10) + sc[i]];
  }

  for (int kt = 0; kt < 16; kt++) {
    __syncthreads();
    #pragma unroll
    for (int i = 0; i < 2; i++) {
      *(f32x4*)&Ks[sr[i]][sc[i]] = kreg[i];
      *(f32x4*)&Vs[sr[i]][sc[i]] = vreg[i];
    }
    __syncthreads();
    if (kt < 15) {
      #pragma unroll
      for (int i = 0; i < 2; i++) {
        kreg[i] = *(const f32x4*)&kb[((size_t)((kt + 1) * 64 + sr[i]) << 6) + sc[i]];
        vreg[i] = *(const f32x4*)&vb[((size_t)sr[i] << 10) + (kt + 1) * 64 + sc[i]];
      }
    }

    f32x4 s[2][4] = {};
    #pragma unroll
    for (int ks = 0; ks < 2; ks++) {
      const int kk = ks * 32 + quad * 8;
      short8 b0 = *(const short8*)&Ks[l16][kk];
      short8 b1 = *(const short8*)&Ks[16 + l16][kk];
      short8 b2 = *(const short8*)&Ks[32 + l16][kk];
      short8 b3 = *(const short8*)&Ks[48 + l16][kk];
      s[0][0] = MFMA16(aq[0][ks], b0, s[0][0]);
      s[0][1] = MFMA16(aq[0][ks], b1, s[0][1]);
      s[0][2] = MFMA16(aq[0][ks], b2, s[0][2]);
      s[0][3] = MFMA16(aq[0][ks], b3, s[0][3]);
      s[1][0] = MFMA16(aq[1][ks], b0, s[1][0]);
      s[1][1] = MFMA16(aq[1][ks], b1, s[1][1]);
      s[1][2] = MFMA16(aq[1][ks], b2, s[1][2]);
      s[1][3] = MFMA16(aq[1][ks], b3, s[1][3]);
    }

    #pragma unroll
    for (int rg = 0; rg < 2; rg++) {
      #pragma unroll
      for (int r = 0; r < 4; r++) {
        float p0 = exp2f(s[rg][0][r]);
        float p1 = exp2f(s[rg][1][r]);
        float p2 = exp2f(s[rg][2][r]);
        float p3 = exp2f(s[rg][3][r]);
        lsum[rg][r] += (p0 + p1) + (p2 + p3);
        u32x2 pk;
        pk.x = pack2bf(p0, p1);
        pk.y = pack2bf(p2, p3);
        *(u32x2*)&Ps[rg * 16 + quad * 4 + r][4 * l16] = pk;
      }
    }

    #pragma unroll
    for (int ks = 0; ks < 2; ks++) {
      const int kk = ks * 32 + quad * 8;
      short8 a0 = *(const short8*)&Ps[l16][kk];
      short8 a1 = *(const short8*)&Ps[16 + l16][kk];
      short8 v0 = *(const short8*)&Vs[l16][kk];
      short8 v1 = *(const short8*)&Vs[16 + l16][kk];
      short8 v2 = *(const short8*)&Vs[32 + l16][kk];
      short8 v3 = *(const short8*)&Vs[48 + l16][kk];
      Oacc[0][0] = MFMA16(a0, v0, Oacc[0][0]);
      Oacc[0][1] = MFMA16(a0, v1, Oacc[0][1]);
      Oacc[0][2] = MFMA16(a0, v2, Oacc[0][2]);
      Oacc[0][3] = MFMA16(a0, v3, Oacc[0][3]);
      Oacc[1][0] = MFMA16(a1, v0, Oacc[1][0]);
      Oacc[1][1] = MFMA16(a1, v1, Oacc[1][1]);
      Oacc[1][2] = MFMA16(a1, v2, Oacc[1][2]);
      Oacc[1][3] = MFMA16(a1, v3, Oacc[1][3]);
    }
  }

  const int b = bh / 12, h = bh - (bh / 12) * 12;
  #pragma unroll
  for (int rg = 0; rg < 2; rg++) {
    #pragma unroll
    for (int r = 0; r < 4; r++) {
      float t = lsum[rg][r];
      t += __shfl_xor(t, 1, 64);
      t += __shfl_xor(t, 2, 64);
      t += __shfl_xor(t, 4, 64);
      t += __shfl_xor(t, 8, 64);
      float inv = 1.0f / t;
      int np = q0 + wave * 32 + rg * 16 + quad * 4 + r;
      size_t base = ((size_t)(b * 1024 + np)) * 768 + h * 64;
      #pragma unroll
      for (int j = 0; j < 4; j++)
        o[base + j * 16 + l16] = f2bf(Oacc[rg][j][r] * inv);
    }
  }
}

// ---------------------------------------------------------------------------
extern "C" void kernel_launch(void* const* d_in, const int* in_sizes, int n_in,
                              void* d_out, int out_size, void* d_ws, size_t ws_size,
                              hipStream_t stream) {
  const float* x      = (const float*)d_in[0];
  const float* w_qkv  = (const float*)d_in[1];
  const float* b_qkv  = (const float*)d_in[2];
  const float* w_proj = (const float*)d_in[3];
  const float* b_proj = (const float*)d_in[4];
  const float* q_a    = (const float*)d_in[5];
  const float* q_b    = (const float*)d_in[6];
  const float* k_a    = (const float*)d_in[7];
  const float* k_b    = (const float*)d_in[8];
  const float* v_a    = (const float*)d_in[9];
  const float* v_b    = (const float*)d_in[10];
  const float* o_a    = (const float*)d_in[11];
  const float* o_b    = (const float*)d_in[12];

  char* ws = (char*)d_ws;
  unsigned short* wqkv_eff  = (unsigned short*)(ws + 0);          // 3,538,944
  unsigned short* wproj_eff = (unsigned short*)(ws + 3538944);    // 1,179,648
  unsigned short* xb        = (unsigned short*)(ws + 4718592);    // 12,582,912 (reused as od)
  unsigned short* qd        = (unsigned short*)(ws + 17301504);   // 12,582,912
  unsigned short* kd        = (unsigned short*)(ws + 29884416);   // 12,582,912
  unsigned short* vtd       = (unsigned short*)(ws + 42467328);   // 12,582,912 (end 55,050,240)
  unsigned short* od        = xb;  // xb dead after QKV GEMM

  prep<<<dim3(6144 + 9216), dim3(256), 0, stream>>>(
      x, w_qkv, w_proj, q_a, q_b, k_a, k_b, v_a, v_b, o_a, o_b,
      xb, wqkv_eff, wproj_eff);

  gemm_bt<<<dim3(64, 18), dim3(256), 0, stream>>>(
      xb, wqkv_eff, b_qkv, qd, kd, vtd, nullptr, 768, 2304, 0);

  attn<<<dim3(96, 8), dim3(256), 0, stream>>>(qd, kd, vtd, od);

  gemm_bt<<<dim3(64, 6), dim3(256), 0, stream>>>(
      od, wproj_eff, b_proj, nullptr, nullptr, nullptr, (float*)d_out, 768, 768, 1);
}

// Round 7
// 228.363 us; speedup vs baseline: 1.3283x; 1.3283x over previous
//
#include <hip/hip_runtime.h>

typedef __attribute__((ext_vector_type(8))) short short8;
typedef __attribute__((ext_vector_type(4))) float f32x4;
typedef __attribute__((ext_vector_type(4))) unsigned short u16x4;
typedef __attribute__((ext_vector_type(2))) unsigned int u32x2;

#define MFMA16(a,b,c) __builtin_amdgcn_mfma_f32_16x16x32_bf16((a),(b),(c),0,0,0)

// 0.125 (attn scale) * log2(e), folded into Q at the QKV epilogue.
#define QSCALE 0.1803368801f

__device__ __forceinline__ unsigned short f2bf(float f) {
  unsigned int x = __float_as_uint(f);
  x += 0x7fffu + ((x >> 16) & 1u);
  return (unsigned short)(x >> 16);
}
__device__ __forceinline__ unsigned int pack2bf(float a, float b) {
  unsigned int ua = __float_as_uint(a) + 0x8000u;
  unsigned int ub = __float_as_uint(b) + 0x8000u;
  return __builtin_amdgcn_perm(ub, ua, 0x07060302);
}
// async 16B global -> LDS (dest = wave-uniform base + lane*16)
__device__ __forceinline__ void gload16(const unsigned short* g, unsigned short* l) {
  __builtin_amdgcn_global_load_lds(
      (const __attribute__((address_space(1))) unsigned int*)g,
      (__attribute__((address_space(3))) unsigned int*)l, 16, 0, 0);
}

// ---------------------------------------------------------------------------
// Kernel 1: prep = convert_x (blocks < 6144) + build_weights (rest).
// ---------------------------------------------------------------------------
__global__ __launch_bounds__(256) void prep(
    const float* __restrict__ x,
    const float* __restrict__ w_qkv,
    const float* __restrict__ w_proj,
    const float* __restrict__ q_a, const float* __restrict__ q_b,
    const float* __restrict__ k_a, const float* __restrict__ k_b,
    const float* __restrict__ v_a, const float* __restrict__ v_b,
    const float* __restrict__ o_a, const float* __restrict__ o_b,
    unsigned short* __restrict__ xb,
    unsigned short* __restrict__ wqkv_eff,
    unsigned short* __restrict__ wproj_eff)
{
  int bid = blockIdx.x;
  if (bid < 6144) {
    int i4 = (bid * 256 + threadIdx.x) * 4;
    f32x4 v = *(const f32x4*)&x[i4];
    u16x4 o;
    o.x = f2bf(v.x); o.y = f2bf(v.y); o.z = f2bf(v.z); o.w = f2bf(v.w);
    *(u16x4*)&xb[i4] = o;
    return;
  }
  const int QKV = 2304 * 768;
  int idx = (bid - 6144) * 256 + threadIdx.x;
  if (idx < QKV) {
    int n = idx / 768, c = idx - n * 768;
    int sec = n / 768;
    int nr = n - sec * 768;
    const float* a; const float* b;
    if (sec == 0)      { a = q_a; b = q_b; }
    else if (sec == 1) { a = k_a; b = k_b; }
    else               { a = v_a; b = v_b; }
    float acc = w_qkv[idx];
    #pragma unroll
    for (int r = 0; r < 8; r++)
      acc += b[nr * 8 + r] * a[r * 768 + c];
    wqkv_eff[idx] = f2bf(acc);
  } else {
    int i2 = idx - QKV;
    int n = i2 / 768, c = i2 - n * 768;
    float acc = w_proj[i2];
    #pragma unroll
    for (int r = 0; r < 8; r++)
      acc += o_b[n * 8 + r] * o_a[r * 768 + c];
    wproj_eff[i2] = f2bf(acc);
  }
}

// ---------------------------------------------------------------------------
// Kernel 2/4: C[M,N'] = A[M,K] @ W[N',K]^T + bias. 1-barrier pipelined K-loop,
// BOTH A and W double-buffered in LDS via async global_load_lds(16B):
//   iter k: __syncthreads() (drains staging of buf p issued one full compute
//   phase ago) -> issue stage(k+1 -> buf 1-p) -> compute from buf p.
// All state in LDS; registers = 64 acc + addressing only (no spills; R6's
// register A-prefetch spilled: WRITE_SIZE 37->127MB).
// XOR-swizzled unpadded LDS (slot (lane&7), source chunk (lane&7)^(row&7));
// read back at slot (cs ^ (l16&7)) -> 0 bank conflicts (R5-verified).
// 128x128 tile, BK=64, 2x2 wave grid, 64x64 out/wave. Requires K/64 even.
// mode 0 (QKV): Q*QSCALE -> q[BH][N][64]; K -> k[BH][N][64];
//               V -> vt[BH][64][1024], key-permuted cols (4*(np&15)+((np>>4)&3)).
// mode 1: fp32 row-major store (final output).
// ---------------------------------------------------------------------------
#define GSTEP(kk, p)                                                          \
  {                                                                           \
    __syncthreads();                                                          \
    const int kn_ = ((kk) + 1) << 6;                                          \
    if (kn_ < K) {                                                            \
      _Pragma("unroll")                                                       \
      for (int t = 0; t < 4; t++)                                             \
        gload16(gA[t] + kn_, &As[1 - (p)][ls_off[t]]);                        \
      _Pragma("unroll")                                                       \
      for (int t = 0; t < 4; t++)                                             \
        gload16(gW[t] + kn_, &Ws[1 - (p)][ls_off[t]]);                        \
    }                                                                         \
    _Pragma("unroll")                                                         \
    for (int ks = 0; ks < 2; ks++) {                                          \
      const int cs = ks * 4 + quad;                                           \
      short8 a_[4], b_[4];                                                    \
      _Pragma("unroll")                                                       \
      for (int t = 0; t < 4; t++) {                                           \
        a_[t] = *(const short8*)&As[p][(wr * 64 + t * 16 + l16) * 64 +        \
                                       ((cs ^ swz) << 3)];                    \
        b_[t] = *(const short8*)&Ws[p][(wc * 64 + t * 16 + l16) * 64 +        \
                                       ((cs ^ swz) << 3)];                    \
      }                                                                       \
      _Pragma("unroll")                                                       \
      for (int i = 0; i < 4; i++)                                             \
        _Pragma("unroll")                                                     \
        for (int j = 0; j < 4; j++)                                           \
          acc[i][j] = MFMA16(a_[i], b_[j], acc[i][j]);                        \
    }                                                                         \
  }

__global__ __launch_bounds__(256) void gemm_bt(
    const unsigned short* __restrict__ A,
    const unsigned short* __restrict__ W,
    const float* __restrict__ bias,
    unsigned short* __restrict__ out0,
    unsigned short* __restrict__ out1,
    unsigned short* __restrict__ out2,
    float* __restrict__ outf,
    int K, int Ncols, int mode)
{
  __shared__ alignas(16) unsigned short As[2][128 * 64];  // 2 x 16 KB
  __shared__ alignas(16) unsigned short Ws[2][128 * 64];  // 2 x 16 KB
  const int tid  = threadIdx.x;
  const int wave = tid >> 6;
  const int lane = tid & 63;
  const int quad = lane >> 4;
  const int l16  = lane & 15;
  const int wr   = wave >> 1, wc = wave & 1;   // 2x2 wave grid
  const int m0 = blockIdx.x * 128;
  const int n0 = blockIdx.y * 128;
  const int swz = l16 & 7;

  // staging: wave stages rows [wave*32, +32) of A and W; 4 instrs each,
  // lane -> row +(lane>>3), global chunk (lane&7)^(row&7), LDS slot (lane&7)
  // (equals the HW's base+lane*16 pattern exactly).
  const int lrow   = lane >> 3;
  const int lchunk = (lane & 7) ^ lrow;
  const unsigned short* gA[4];
  const unsigned short* gW[4];
  int ls_off[4];
  #pragma unroll
  for (int t = 0; t < 4; t++) {
    int rr = wave * 32 + t * 8;
    gA[t]     = A + (size_t)(m0 + rr + lrow) * K + lchunk * 8;
    gW[t]     = W + (size_t)(n0 + rr + lrow) * K + lchunk * 8;
    ls_off[t] = (rr + lrow) * 64 + (lane & 7) * 8;
  }

  f32x4 acc[4][4] = {};

  // prologue: stage k=0 into buf 0
  #pragma unroll
  for (int t = 0; t < 4; t++) gload16(gA[t], &As[0][ls_off[t]]);
  #pragma unroll
  for (int t = 0; t < 4; t++) gload16(gW[t], &Ws[0][ls_off[t]]);

  const int nit = K >> 6;                      // even (768/64 = 12)
  for (int k = 0; k < nit; k += 2) {
    GSTEP(k,     0);
    GSTEP(k + 1, 1);
  }

  float bv[4];
  #pragma unroll
  for (int j = 0; j < 4; j++) bv[j] = bias[n0 + wc * 64 + j * 16 + l16];

  if (mode == 0) {
    const int sec = n0 / 768;                       // uniform (768 % 128 == 0)
    const int h   = ((n0 % 768) >> 6) + wc;         // wave's head
    unsigned short* dst = (sec == 0) ? out0 : ((sec == 1) ? out1 : out2);
    const float scl = (sec == 0) ? QSCALE : 1.0f;
    #pragma unroll
    for (int i = 0; i < 4; i++) {
      #pragma unroll
      for (int r = 0; r < 4; r++) {
        int m  = m0 + wr * 64 + i * 16 + quad * 4 + r;
        int bb = m >> 10, np = m & 1023;
        int bh = bb * 12 + h;
        int npp = (np & ~63) | ((np & 15) * 4 + ((np >> 4) & 3)); // key perm
        #pragma unroll
        for (int j = 0; j < 4; j++) {
          int d = j * 16 + l16;
          float v = (acc[i][j][r] + bv[j]) * scl;
          if (sec < 2) dst[((size_t)bh << 16) + ((size_t)np << 6) + d] = f2bf(v);
          else         dst[((size_t)bh << 16) + ((size_t)d << 10) + npp] = f2bf(v);
        }
      }
    }
  } else {
    #pragma unroll
    for (int i = 0; i < 4; i++) {
      #pragma unroll
      for (int r = 0; r < 4; r++) {
        int m = m0 + wr * 64 + i * 16 + quad * 4 + r;
        #pragma unroll
        for (int j = 0; j < 4; j++)
          outf[(size_t)m * Ncols + n0 + wc * 64 + j * 16 + l16] = acc[i][j][r] + bv[j];
      }
    }
  }
}

// ---------------------------------------------------------------------------
// Kernel 3: flash attention (unchanged).
// ---------------------------------------------------------------------------
__global__ __launch_bounds__(256) void attn(
    const unsigned short* __restrict__ q,
    const unsigned short* __restrict__ k,
    const unsigned short* __restrict__ vt,
    unsigned short* __restrict__ o)
{
  __shared__ alignas(16) unsigned short Qs[128][72];
  __shared__ alignas(16) unsigned short Ks[64][72];
  __shared__ alignas(16) unsigned short Vs[64][72];
  const int tid  = threadIdx.x;
  const int wave = tid >> 6;
  const int lane = tid & 63;
  const int quad = lane >> 4;
  const int l16  = lane & 15;
  const int bh = blockIdx.x;
  const int q0 = blockIdx.y * 128;
  const unsigned short* qb = q  + ((size_t)bh << 16);
  const unsigned short* kb = k  + ((size_t)bh << 16);
  const unsigned short* vb = vt + ((size_t)bh << 16);

  #pragma unroll
  for (int i = 0; i < 4; i++) {
    int flat = tid + i * 256;
    int r = flat >> 3, ck = (flat & 7) << 3;
    *(f32x4*)&Qs[r][ck] = *(const f32x4*)&qb[((size_t)(q0 + r) << 6) + ck];
  }
  __syncthreads();
  short8 aq[2][2];
  #pragma unroll
  for (int rg = 0; rg < 2; rg++)
    #pragma unroll
    for (int ks = 0; ks < 2; ks++)
      aq[rg][ks] = *(const short8*)&Qs[wave * 32 + rg * 16 + l16][ks * 32 + quad * 8];
  __syncthreads();  // Q consumed; Qs becomes wave-private P scratch
  unsigned short (*Ps)[72] = (unsigned short (*)[72])(&Qs[wave * 32][0]);

  f32x4 Oacc[2][4] = {};
  float lsum[2][4] = {};

  int sr[2], sc[2];
  #pragma unroll
  for (int i = 0; i < 2; i++) { int f = tid + i * 256; sr[i] = f >> 3; sc[i] = (f & 7) << 3; }

  f32x4 kreg[2], vreg[2];
  #pragma unroll
  for (int i = 0; i < 2; i++) {
    kreg[i] = *(const f32x4*)&kb[((size_t)sr[i] << 6) + sc[i]];
    vreg[i] = *(const f32x4*)&vb[((size_t)sr[i] << 10) + sc[i]];
  }

  for (int kt = 0; kt < 16; kt++) {
    __syncthreads();
    #pragma unroll
    for (int i = 0; i < 2; i++) {
      *(f32x4*)&Ks[sr[i]][sc[i]] = kreg[i];
      *(f32x4*)&Vs[sr[i]][sc[i]] = vreg[i];
    }
    __syncthreads();
    if (kt < 15) {
      #pragma unroll
      for (int i = 0; i < 2; i++) {
        kreg[i] = *(const f32x4*)&kb[((size_t)((kt + 1) * 64 + sr[i]) << 6) + sc[i]];
        vreg[i] = *(const f32x4*)&vb[((size_t)sr[i] << 10) + (kt + 1) * 64 + sc[i]];
      }
    }

    f32x4 s[2][4] = {};
    #pragma unroll
    for (int ks = 0; ks < 2; ks++) {
      const int kk = ks * 32 + quad * 8;
      short8 b0 = *(const short8*)&Ks[l16][kk];
      short8 b1 = *(const short8*)&Ks[16 + l16][kk];
      short8 b2 = *(const short8*)&Ks[32 + l16][kk];
      short8 b3 = *(const short8*)&Ks[48 + l16][kk];
      s[0][0] = MFMA16(aq[0][ks], b0, s[0][0]);
      s[0][1] = MFMA16(aq[0][ks], b1, s[0][1]);
      s[0][2] = MFMA16(aq[0][ks], b2, s[0][2]);
      s[0][3] = MFMA16(aq[0][ks], b3, s[0][3]);
      s[1][0] = MFMA16(aq[1][ks], b0, s[1][0]);
      s[1][1] = MFMA16(aq[1][ks], b1, s[1][1]);
      s[1][2] = MFMA16(aq[1][ks], b2, s[1][2]);
      s[1][3] = MFMA16(aq[1][ks], b3, s[1][3]);
    }

    #pragma unroll
    for (int rg = 0; rg < 2; rg++) {
      #pragma unroll
      for (int r = 0; r < 4; r++) {
        float p0 = exp2f(s[rg][0][r]);
        float p1 = exp2f(s[rg][1][r]);
        float p2 = exp2f(s[rg][2][r]);
        float p3 = exp2f(s[rg][3][r]);
        lsum[rg][r] += (p0 + p1) + (p2 + p3);
        u32x2 pk;
        pk.x = pack2bf(p0, p1);
        pk.y = pack2bf(p2, p3);
        *(u32x2*)&Ps[rg * 16 + quad * 4 + r][4 * l16] = pk;
      }
    }

    #pragma unroll
    for (int ks = 0; ks < 2; ks++) {
      const int kk = ks * 32 + quad * 8;
      short8 a0 = *(const short8*)&Ps[l16][kk];
      short8 a1 = *(const short8*)&Ps[16 + l16][kk];
      short8 v0 = *(const short8*)&Vs[l16][kk];
      short8 v1 = *(const short8*)&Vs[16 + l16][kk];
      short8 v2 = *(const short8*)&Vs[32 + l16][kk];
      short8 v3 = *(const short8*)&Vs[48 + l16][kk];
      Oacc[0][0] = MFMA16(a0, v0, Oacc[0][0]);
      Oacc[0][1] = MFMA16(a0, v1, Oacc[0][1]);
      Oacc[0][2] = MFMA16(a0, v2, Oacc[0][2]);
      Oacc[0][3] = MFMA16(a0, v3, Oacc[0][3]);
      Oacc[1][0] = MFMA16(a1, v0, Oacc[1][0]);
      Oacc[1][1] = MFMA16(a1, v1, Oacc[1][1]);
      Oacc[1][2] = MFMA16(a1, v2, Oacc[1][2]);
      Oacc[1][3] = MFMA16(a1, v3, Oacc[1][3]);
    }
  }

  const int b = bh / 12, h = bh - (bh / 12) * 12;
  #pragma unroll
  for (int rg = 0; rg < 2; rg++) {
    #pragma unroll
    for (int r = 0; r < 4; r++) {
      float t = lsum[rg][r];
      t += __shfl_xor(t, 1, 64);
      t += __shfl_xor(t, 2, 64);
      t += __shfl_xor(t, 4, 64);
      t += __shfl_xor(t, 8, 64);
      float inv = 1.0f / t;
      int np = q0 + wave * 32 + rg * 16 + quad * 4 + r;
      size_t base = ((size_t)(b * 1024 + np)) * 768 + h * 64;
      #pragma unroll
      for (int j = 0; j < 4; j++)
        o[base + j * 16 + l16] = f2bf(Oacc[rg][j][r] * inv);
    }
  }
}

// ---------------------------------------------------------------------------
extern "C" void kernel_launch(void* const* d_in, const int* in_sizes, int n_in,
                              void* d_out, int out_size, void* d_ws, size_t ws_size,
                              hipStream_t stream) {
  const float* x      = (const float*)d_in[0];
  const float* w_qkv  = (const float*)d_in[1];
  const float* b_qkv  = (const float*)d_in[2];
  const float* w_proj = (const float*)d_in[3];
  const float* b_proj = (const float*)d_in[4];
  const float* q_a    = (const float*)d_in[5];
  const float* q_b    = (const float*)d_in[6];
  const float* k_a    = (const float*)d_in[7];
  const float* k_b    = (const float*)d_in[8];
  const float* v_a    = (const float*)d_in[9];
  const float* v_b    = (const float*)d_in[10];
  const float* o_a    = (const float*)d_in[11];
  const float* o_b    = (const float*)d_in[12];

  char* ws = (char*)d_ws;
  unsigned short* wqkv_eff  = (unsigned short*)(ws + 0);          // 3,538,944
  unsigned short* wproj_eff = (unsigned short*)(ws + 3538944);    // 1,179,648
  unsigned short* xb        = (unsigned short*)(ws + 4718592);    // 12,582,912 (reused as od)
  unsigned short* qd        = (unsigned short*)(ws + 17301504);   // 12,582,912
  unsigned short* kd        = (unsigned short*)(ws + 29884416);   // 12,582,912
  unsigned short* vtd       = (unsigned short*)(ws + 42467328);   // 12,582,912 (end 55,050,240)
  unsigned short* od        = xb;  // xb dead after QKV GEMM

  prep<<<dim3(6144 + 9216), dim3(256), 0, stream>>>(
      x, w_qkv, w_proj, q_a, q_b, k_a, k_b, v_a, v_b, o_a, o_b,
      xb, wqkv_eff, wproj_eff);

  gemm_bt<<<dim3(64, 18), dim3(256), 0, stream>>>(
      xb, wqkv_eff, b_qkv, qd, kd, vtd, nullptr, 768, 2304, 0);

  attn<<<dim3(96, 8), dim3(256), 0, stream>>>(qd, kd, vtd, od);

  gemm_bt<<<dim3(64, 6), dim3(256), 0, stream>>>(
      od, wproj_eff, b_proj, nullptr, nullptr, nullptr, (float*)d_out, 768, 768, 1);
}